// Round 8
// baseline (339.561 us; speedup 1.0000x reference)
//
#include <hip/hip_runtime.h>
#include <hip/hip_bf16.h>
#include <cstdint>

#define S_LEN 4096
#define D_DIM 512
#define NWIN  511
#define KDIM  8192
#define TR2   1032                // 8*128+8 x-rows per union A-tile (BM=128)

typedef __attribute__((ext_vector_type(8))) short short8;
typedef __attribute__((ext_vector_type(4))) short short4v;
typedef __attribute__((ext_vector_type(4))) float f32x4;

__device__ __forceinline__ unsigned short f2b(float f) {
    union { float f; unsigned int u; } v; v.f = f;
    unsigned int r = v.u + 0x7FFFu + ((v.u >> 16) & 1u);
    return (unsigned short)(r >> 16);
}

// ---------------------------------------------------------------------------
// Pre-pass: pack W [8192][512] fp32 -> bf16 MFMA-fragment order at K=32
// granularity, slice-major. Slice q2 = (c0*2+k32)*16 + t  (c0: 64-col group,
// k32: half, t: token row). Fragment content (verified mapping R1-R7):
//   value = W[t*512 + c0*64 + k32*32 + hi*8 + e][64*w + 16*n + r15]
//   at short8 offset q2*2048 + w*256 + n*64 + lane.
// Each q2 slice is a contiguous 512 KB stream -> per-XCD L2 residency.
// ---------------------------------------------------------------------------
__global__ void wpack2_kernel(const float* __restrict__ W, short8* __restrict__ pk) {
    __shared__ float tile[64][68];
    const int b2 = blockIdx.x;           // (t*8+c0)*8 + w
    const int s = b2 >> 3, w = b2 & 7;
    const int t = s >> 3, c0 = s & 7;
    const int tid = threadIdx.x;
    {
        int r = tid >> 2, c4 = (tid & 3) << 4;
        const float* src = W + (size_t)(t * 512 + c0 * 64 + r) * D_DIM + (w << 6) + c4;
#pragma unroll
        for (int j = 0; j < 4; ++j) {
            float4 v = *(const float4*)(src + 4 * j);
            tile[r][c4 + 4 * j + 0] = v.x;
            tile[r][c4 + 4 * j + 1] = v.y;
            tile[r][c4 + 4 * j + 2] = v.z;
            tile[r][c4 + 4 * j + 3] = v.w;
        }
    }
    __syncthreads();
    const int lane = tid & 63, f2 = tid >> 6;
    const int r15 = lane & 15, hi = lane >> 4;
#pragma unroll
    for (int ff = 0; ff < 2; ++ff) {
        int f = f2 * 2 + ff;
        int n = f >> 1, k32 = f & 1;
        int q2 = (c0 * 2 + k32) * 16 + t;
        short8 u;
#pragma unroll
        for (int e = 0; e < 8; ++e)
            u[e] = (short)f2b(tile[k32 * 32 + hi * 8 + e][n * 16 + r15]);
        pk[(size_t)q2 * 2048 + w * 256 + n * 64 + lane] = u;
    }
}

// ---------------------------------------------------------------------------
// Kernel A: windows-GEMM + bias + exact GELU -> hbuf (fp32).
// Block: (batch b, windows [n0,n0+128), col-half nc). 16 waves (4/SIMD),
// wave tile 128 rows x 16 cols -> acc[8] f32x4, 1 B-frag per TSTEP.
// nc pairs are 8 blockIdx apart -> same XCD under round-robin -> A L2-shared.
// A: 32-col slices, 2 x 64.5 KB LDS dbuf, 8B-slot XOR swizzle ^((r>>3)&7)
//    (2-way max read+write = free), issue-early/convert-late, 1 barrier/slice.
// B: slice-major pk -> registers, depth-2 prefetch over 4 rotating frags.
// ---------------------------------------------------------------------------
__global__ __launch_bounds__(1024)
void gemm2_kernel(const float* __restrict__ x,
                  const short8* __restrict__ pk,
                  const float* __restrict__ bias,
                  float* __restrict__ hbuf)
{
    __shared__ __align__(16) unsigned short lsA[2][TR2 * 32];   // 2 x 64.5 KB

    const int p  = blockIdx.x;
    const int nc = (p >> 3) & 1;
    const int g  = ((p >> 4) << 3) | (p & 7);   // 0..127; pair = p, p+8 (same XCD)
    const int b  = g >> 2;
    const int n0 = (g & 3) << 7;                // window base (x128)
    const int tid  = threadIdx.x;
    const int lane = tid & 63, wid = tid >> 6;
    const int r15 = lane & 15, hi = lane >> 4;
    const int boff = (nc * 4 + (wid >> 2)) * 256 + (wid & 3) * 64 + lane;
    const float* xb = x + (size_t)b * S_LEN * D_DIM;

    f32x4 acc[8] = {};
    short8 B0, B1, B2, B3;
    float4 ta[2][2];   // 2 staging chunks in flight, literal-indexed

#define CISSUE(J, SL)                                                          \
    {                                                                          \
        if ((J) < 4 || tid < 32) {                                             \
            const int c_ = tid + ((J) << 10);                                  \
            const int r_ = c_ >> 2, kc_ = c_ & 3;                              \
            int gr_ = 8 * n0 + r_;                                             \
            if (gr_ > S_LEN - 1) gr_ = S_LEN - 1;                              \
            const float* s_ = xb + (size_t)gr_ * D_DIM + (SL) * 32 + (kc_ << 3); \
            ta[(J) & 1][0] = *(const float4*)s_;                               \
            ta[(J) & 1][1] = *(const float4*)(s_ + 4);                         \
        }                                                                      \
    }

#define CWRITE(J, DST)                                                         \
    {                                                                          \
        if ((J) < 4 || tid < 32) {                                             \
            const int c_ = tid + ((J) << 10);                                  \
            const int r_ = c_ >> 2, kc_ = c_ & 3;                              \
            const int sw_ = (r_ >> 3) & 7;                                     \
            short4v lo_, hh_;                                                  \
            lo_[0] = (short)f2b(ta[(J) & 1][0].x);                             \
            lo_[1] = (short)f2b(ta[(J) & 1][0].y);                             \
            lo_[2] = (short)f2b(ta[(J) & 1][0].z);                             \
            lo_[3] = (short)f2b(ta[(J) & 1][0].w);                             \
            hh_[0] = (short)f2b(ta[(J) & 1][1].x);                             \
            hh_[1] = (short)f2b(ta[(J) & 1][1].y);                             \
            hh_[2] = (short)f2b(ta[(J) & 1][1].z);                             \
            hh_[3] = (short)f2b(ta[(J) & 1][1].w);                             \
            *(short4v*)&(DST)[r_ * 32 + ((((kc_ << 1)    ) ^ sw_) << 2)] = lo_; \
            *(short4v*)&(DST)[r_ * 32 + ((((kc_ << 1) | 1) ^ sw_) << 2)] = hh_; \
        }                                                                      \
    }

#define TSTEP(T, LA, BU, BL)                                                   \
    {                                                                          \
        BL = pk[(size_t)((u0 + (T) + 2) & 255) * 2048 + boff];                 \
        const int swr = (r15 + ((T) >> 3)) & 7;                                \
        _Pragma("unroll")                                                      \
        for (int m = 0; m < 8; ++m) {                                          \
            const int rb = (8 * ((m << 4) + r15) + (T)) * 32;                  \
            short4v alo = *(const short4v*)&(LA)[rb + ((( (hi << 1)     ) ^ swr) << 2)]; \
            short4v ahi = *(const short4v*)&(LA)[rb + ((( (hi << 1) | 1 ) ^ swr) << 2)]; \
            short8 afr = __builtin_shufflevector(alo, ahi, 0, 1, 2, 3, 4, 5, 6, 7);      \
            acc[m] = __builtin_amdgcn_mfma_f32_16x16x32_bf16(afr, BU, acc[m], 0, 0, 0);  \
        }                                                                      \
    }

    // ---- prologue: B(q2=0,1) in flight, stage slice 0 into buf 0 ----
    B0 = pk[(size_t)0 * 2048 + boff];
    B1 = pk[(size_t)1 * 2048 + boff];
    CISSUE(0, 0) CISSUE(1, 0) CWRITE(0, lsA[0]) CISSUE(2, 0) CWRITE(1, lsA[0])
    CISSUE(3, 0) CWRITE(2, lsA[0]) CISSUE(4, 0) CWRITE(3, lsA[0]) CWRITE(4, lsA[0])
    asm volatile("s_waitcnt lgkmcnt(0)" ::: "memory");
    __builtin_amdgcn_s_barrier();
    __builtin_amdgcn_sched_barrier(0);

    // ---- main loop: 16 K-slices (32 cols each) x 16 t-steps ----
    for (int sl = 0; sl < 16; ++sl) {
        const unsigned short* La = lsA[sl & 1];
        unsigned short* Ln = lsA[(sl + 1) & 1];
        const int u0 = sl << 4;
        const int snx = sl + 1;
        const int pf = (sl < 15);

        TSTEP(0, La, B0, B2)
        if (pf) CISSUE(0, snx)
        TSTEP(1, La, B1, B3)
        if (pf) CISSUE(1, snx)
        TSTEP(2, La, B2, B0)
        TSTEP(3, La, B3, B1)
        if (pf) { CWRITE(0, Ln) CISSUE(2, snx) }
        TSTEP(4, La, B0, B2)
        TSTEP(5, La, B1, B3)
        if (pf) { CWRITE(1, Ln) CISSUE(3, snx) }
        TSTEP(6, La, B2, B0)
        TSTEP(7, La, B3, B1)
        if (pf) { CWRITE(2, Ln) CISSUE(4, snx) }
        TSTEP(8, La, B0, B2)
        TSTEP(9, La, B1, B3)
        if (pf) CWRITE(3, Ln)
        TSTEP(10, La, B2, B0)
        TSTEP(11, La, B3, B1)
        if (pf) CWRITE(4, Ln)
        TSTEP(12, La, B0, B2)
        TSTEP(13, La, B1, B3)
        TSTEP(14, La, B2, B0)
        TSTEP(15, La, B3, B1)

        asm volatile("s_waitcnt lgkmcnt(0)" ::: "memory");
        __builtin_amdgcn_s_barrier();
        __builtin_amdgcn_sched_barrier(0);
    }
#undef TSTEP
#undef CISSUE
#undef CWRITE

    // ---- epilogue: bias + exact GELU -> hbuf[b][win][d] ----
    const int d = nc * 256 + (wid << 4) + r15;
    const float bias1 = bias[d];
    float* hb = hbuf + (size_t)b * NWIN * D_DIM;
#pragma unroll
    for (int m = 0; m < 8; ++m) {
#pragma unroll
        for (int r = 0; r < 4; ++r) {
            int win = n0 + (m << 4) + (hi << 2) + r;
            if (win < NWIN) {
                float h = acc[m][r] + bias1;
                hb[(size_t)win * D_DIM + d] =
                    0.5f * h * (1.0f + erff(h * 0.70710678118654752f));
            }
        }
    }
}

// ---------------------------------------------------------------------------
// Kernel B: row LayerNorm over D=512. One wave per row, grid-stride. (R4-proven)
// ---------------------------------------------------------------------------
__global__ __launch_bounds__(256, 8)
void ln_kernel(const float* __restrict__ h, const float* __restrict__ gamma,
               const float* __restrict__ beta, float* __restrict__ out, int nrows)
{
    const int lane = threadIdx.x & 63;
    const int wv = blockIdx.x * 4 + (threadIdx.x >> 6);
    const int nw = gridDim.x * 4;
    float gm[8], bt[8];
#pragma unroll
    for (int j = 0; j < 8; ++j) {
        gm[j] = gamma[lane * 8 + j];
        bt[j] = beta[lane * 8 + j];
    }
    for (int row = wv; row < nrows; row += nw) {
        const float* src = h + (size_t)row * D_DIM + lane * 8;
        float4 v0 = *(const float4*)src;
        float4 v1 = *(const float4*)(src + 4);
        float s = v0.x + v0.y + v0.z + v0.w + v1.x + v1.y + v1.z + v1.w;
        float q = v0.x * v0.x + v0.y * v0.y + v0.z * v0.z + v0.w * v0.w +
                  v1.x * v1.x + v1.y * v1.y + v1.z * v1.z + v1.w * v1.w;
#pragma unroll
        for (int msk = 1; msk < 64; msk <<= 1) {
            s += __shfl_xor(s, msk, 64);
            q += __shfl_xor(q, msk, 64);
        }
        float mu  = s * (1.0f / 512.0f);
        float inv = rsqrtf(q * (1.0f / 512.0f) - mu * mu + 1e-5f);
        float o[8] = { v0.x, v0.y, v0.z, v0.w, v1.x, v1.y, v1.z, v1.w };
        float4 r0, r1;
        r0.x = (o[0] - mu) * inv * gm[0] + bt[0];
        r0.y = (o[1] - mu) * inv * gm[1] + bt[1];
        r0.z = (o[2] - mu) * inv * gm[2] + bt[2];
        r0.w = (o[3] - mu) * inv * gm[3] + bt[3];
        r1.x = (o[4] - mu) * inv * gm[4] + bt[4];
        r1.y = (o[5] - mu) * inv * gm[5] + bt[5];
        r1.z = (o[6] - mu) * inv * gm[6] + bt[6];
        r1.w = (o[7] - mu) * inv * gm[7] + bt[7];
        float* dst = out + (size_t)row * D_DIM + lane * 8;
        *(float4*)dst = r0;
        *(float4*)(dst + 4) = r1;
    }
}

// Fallback (tiny ws): naive correct kernel.
__global__ void naive_kernel(const float* __restrict__ x, const float* __restrict__ W,
                             const float* __restrict__ bias, const float* __restrict__ gamma,
                             const float* __restrict__ beta, float* __restrict__ out) {
    __shared__ float hrow[D_DIM];
    __shared__ float red[2];
    const int b = blockIdx.x / NWIN, win = blockIdx.x % NWIN;
    const int d = threadIdx.x;
    float a = 0.f;
    for (int t = 0; t < 16; ++t) {
        const float* xr = x + ((size_t)b * S_LEN + 8 * win + t) * D_DIM;
        const float* wr = W + (size_t)t * D_DIM * D_DIM;
        for (int k = 0; k < D_DIM; ++k) a += xr[k] * wr[(size_t)k * D_DIM + d];
    }
    a += bias[d];
    a = 0.5f * a * (1.0f + erff(a * 0.70710678118654752f));
    hrow[d] = a;
    __syncthreads();
    if (d == 0) {
        float s = 0.f, q = 0.f;
        for (int k = 0; k < D_DIM; ++k) { s += hrow[k]; q += hrow[k] * hrow[k]; }
        float mu = s / D_DIM;
        red[0] = mu; red[1] = rsqrtf(q / D_DIM - mu * mu + 1e-5f);
    }
    __syncthreads();
    out[((size_t)b * NWIN + win) * D_DIM + d] = (a - red[0]) * red[1] * gamma[d] + beta[d];
}

extern "C" void kernel_launch(void* const* d_in, const int* in_sizes, int n_in,
                              void* d_out, int out_size, void* d_ws, size_t ws_size,
                              hipStream_t stream) {
    const float* x     = (const float*)d_in[0];
    const float* W     = (const float*)d_in[1];
    const float* bias  = (const float*)d_in[2];
    const float* gamma = (const float*)d_in[3];
    const float* beta  = (const float*)d_in[4];
    float* out = (float*)d_out;

    const size_t pk_bytes = (size_t)KDIM * D_DIM * sizeof(unsigned short);     // 8 MB
    const size_t h_bytes  = (size_t)32 * NWIN * D_DIM * sizeof(float);         // 33.5 MB

    if (ws_size >= pk_bytes + h_bytes) {          // proven available (R4)
        short8* pk = (short8*)d_ws;
        float* hbuf = (float*)((char*)d_ws + pk_bytes);
        wpack2_kernel<<<1024, 256, 0, stream>>>(W, pk);
        gemm2_kernel<<<256, 1024, 0, stream>>>(x, pk, bias, hbuf);
        ln_kernel<<<1024, 256, 0, stream>>>(hbuf, gamma, beta, out, 32 * NWIN);
    } else {
        naive_kernel<<<32 * NWIN, D_DIM, 0, stream>>>(x, W, bias, gamma, beta, out);
    }
}

// Round 9
// 194.166 us; speedup vs baseline: 1.7488x; 1.7488x over previous
//
#include <hip/hip_runtime.h>
#include <hip/hip_bf16.h>
#include <cstdint>

#define S_LEN 4096
#define D_DIM 512
#define NWIN  511
#define KDIM  8192
#define TR3   1032                // 8*128+8 x-rows per union A-tile (BM=128)
#define ROWB  72                  // padded row bytes (32 bf16 cols = 64 B + 8 pad)

typedef __attribute__((ext_vector_type(8))) short short8;
typedef __attribute__((ext_vector_type(4))) short short4v;
typedef __attribute__((ext_vector_type(4))) float f32x4;

__device__ __forceinline__ unsigned short f2b(float f) {
    union { float f; unsigned int u; } v; v.f = f;
    unsigned int r = v.u + 0x7FFFu + ((v.u >> 16) & 1u);
    return (unsigned short)(r >> 16);
}

// ---------------------------------------------------------------------------
// Pre-pass (verified R8): pack W [8192][512] fp32 -> bf16 fragments, K=32
// slice-major. q2 = (c0*2+k32)*16 + t. Fragment content:
//   value = W[t*512 + c0*64 + k32*32 + hi*8 + e][64*w + 16*n + r15]
//   at short8 offset q2*2048 + w*256 + n*64 + lane.
// q2 is the linear B-stream index: slice sl=q2>>4 covers x cols [32*sl,+32).
// ---------------------------------------------------------------------------
__global__ void wpack2_kernel(const float* __restrict__ W, short8* __restrict__ pk) {
    __shared__ float tile[64][68];
    const int b2 = blockIdx.x;           // (t*8+c0)*8 + w
    const int s = b2 >> 3, w = b2 & 7;
    const int t = s >> 3, c0 = s & 7;
    const int tid = threadIdx.x;
    {
        int r = tid >> 2, c4 = (tid & 3) << 4;
        const float* src = W + (size_t)(t * 512 + c0 * 64 + r) * D_DIM + (w << 6) + c4;
#pragma unroll
        for (int j = 0; j < 4; ++j) {
            float4 v = *(const float4*)(src + 4 * j);
            tile[r][c4 + 4 * j + 0] = v.x;
            tile[r][c4 + 4 * j + 1] = v.y;
            tile[r][c4 + 4 * j + 2] = v.z;
            tile[r][c4 + 4 * j + 3] = v.w;
        }
    }
    __syncthreads();
    const int lane = tid & 63, f2 = tid >> 6;
    const int r15 = lane & 15, hi = lane >> 4;
#pragma unroll
    for (int ff = 0; ff < 2; ++ff) {
        int f = f2 * 2 + ff;
        int n = f >> 1, k32 = f & 1;
        int q2 = (c0 * 2 + k32) * 16 + t;
        short8 u;
#pragma unroll
        for (int e = 0; e < 8; ++e)
            u[e] = (short)f2b(tile[k32 * 32 + hi * 8 + e][n * 16 + r15]);
        pk[(size_t)q2 * 2048 + w * 256 + n * 64 + lane] = u;
    }
}

// ---------------------------------------------------------------------------
// Kernel A: windows-GEMM + bias + exact GELU -> hbuf (fp32).
// Block: (batch b, windows [win0,win0+128), col-half nc). 512 thr, 8 waves
// (2 row x 4 col), wave tile 64x64 (R6-proven TSTEP geometry, K=32 MFMA).
// nc = XCD-half (bid&7)>>2 -> each XCD L2 holds exactly its 4 MB pk half;
// B stream linear in q2 (256 KB hot window/slice) -> L2-resident.
// A: 16 slices of 32 cols; 2 x 74.3 KB LDS dbuf, 72-B padded rows (full
// 32-bank coverage), XOR slot swizzle; issue-early/write-late chunks
// (R6-proven schedule); ONE barrier per slice.
// ---------------------------------------------------------------------------
__global__ __launch_bounds__(512, 1)
void gemm3_kernel(const float* __restrict__ x,
                  const short8* __restrict__ pk,
                  const float* __restrict__ bias,
                  float* __restrict__ hbuf)
{
    __shared__ __align__(16) unsigned char lsA[2][TR3 * ROWB];   // 2 x 74.3 KB

    const int bid = blockIdx.x;
    const int nc  = (bid & 7) >> 2;                 // XCD half -> pk half
    const int g   = ((bid >> 3) << 2) | (bid & 3);  // 0..127
    const int b   = g >> 2;
    const int win0 = (g & 3) << 7;                  // window base (x128)
    const int tid = threadIdx.x;
    const int lane = tid & 63, wid = tid >> 6;
    const int wr = wid >> 2, wc = wid & 3;
    const int r15 = lane & 15, hi = lane >> 4;
    const int boff = ((nc * 4 + wc) << 8) + lane;   // short8 units
    const float* xb = x + (size_t)b * S_LEN * D_DIM;

    f32x4 acc[4][4] = {};
    short8 Bc[4], Bn[4];
    float4 ta[2][2];   // 2 staging chunks in flight, literal-indexed

#define CISSUE(J, Q)                                                           \
    {                                                                          \
        if ((J) < 8 || tid < 32) {                                             \
            const int c_ = tid + ((J) << 9);                                   \
            const int r_ = c_ >> 2, k4_ = c_ & 3;                              \
            int gr_ = (win0 << 3) + r_;                                        \
            if (gr_ > S_LEN - 1) gr_ = S_LEN - 1;                              \
            const float* s_ = xb + (size_t)gr_ * D_DIM + ((Q) << 5) + (k4_ << 3); \
            ta[(J) & 1][0] = *(const float4*)s_;                               \
            ta[(J) & 1][1] = *(const float4*)(s_ + 4);                         \
        }                                                                      \
    }

#define CWRITE(J, DST)                                                         \
    {                                                                          \
        if ((J) < 8 || tid < 32) {                                             \
            const int c_ = tid + ((J) << 9);                                   \
            const int r_ = c_ >> 2, k4_ = c_ & 3;                              \
            const int sw_ = (r_ >> 3) & 7;                                     \
            short4v lo_, hh_;                                                  \
            lo_[0] = (short)f2b(ta[(J) & 1][0].x);                             \
            lo_[1] = (short)f2b(ta[(J) & 1][0].y);                             \
            lo_[2] = (short)f2b(ta[(J) & 1][0].z);                             \
            lo_[3] = (short)f2b(ta[(J) & 1][0].w);                             \
            hh_[0] = (short)f2b(ta[(J) & 1][1].x);                             \
            hh_[1] = (short)f2b(ta[(J) & 1][1].y);                             \
            hh_[2] = (short)f2b(ta[(J) & 1][1].z);                             \
            hh_[3] = (short)f2b(ta[(J) & 1][1].w);                             \
            *(short4v*)&(DST)[r_ * ROWB + ((((k4_ << 1)    ) ^ sw_) << 3)] = lo_; \
            *(short4v*)&(DST)[r_ * ROWB + ((((k4_ << 1) | 1) ^ sw_) << 3)] = hh_; \
        }                                                                      \
    }

#define TSTEP(T, LA, BU, BL)                                                   \
    {                                                                          \
        const int q2n = (q16 + (T) + 1) & 255;                                 \
        _Pragma("unroll")                                                      \
        for (int n = 0; n < 4; ++n)                                            \
            BL[n] = pk[(size_t)q2n * 2048 + boff + n * 64];                    \
        __builtin_amdgcn_s_setprio(1);                                         \
        _Pragma("unroll")                                                      \
        for (int m = 0; m < 4; ++m) {                                          \
            const int wl_ = (wr << 6) + (m << 4) + r15;                        \
            const int r_ = (wl_ << 3) + (T);                                   \
            const int sw_ = (r_ >> 3) & 7;                                     \
            const unsigned char* rb_ = (LA) + r_ * ROWB;                       \
            short4v alo = *(const short4v*)&rb_[(((hi << 1)    ) ^ sw_) << 3]; \
            short4v ahi = *(const short4v*)&rb_[(((hi << 1) | 1) ^ sw_) << 3]; \
            short8 afr = __builtin_shufflevector(alo, ahi, 0, 1, 2, 3, 4, 5, 6, 7); \
            _Pragma("unroll")                                                  \
            for (int n = 0; n < 4; ++n)                                        \
                acc[m][n] = __builtin_amdgcn_mfma_f32_16x16x32_bf16(           \
                    afr, BU[n], acc[m][n], 0, 0, 0);                           \
        }                                                                      \
        __builtin_amdgcn_s_setprio(0);                                         \
    }

    // ---- prologue: B(q2=0) in flight, stage slice 0 into buf 0 ----
#pragma unroll
    for (int n = 0; n < 4; ++n)
        Bc[n] = pk[(size_t)boff + n * 64];
    CISSUE(0, 0) CISSUE(1, 0) CWRITE(0, lsA[0]) CISSUE(2, 0) CWRITE(1, lsA[0])
    CISSUE(3, 0) CWRITE(2, lsA[0]) CISSUE(4, 0) CWRITE(3, lsA[0])
    CISSUE(5, 0) CWRITE(4, lsA[0]) CISSUE(6, 0) CWRITE(5, lsA[0])
    CISSUE(7, 0) CWRITE(6, lsA[0]) CISSUE(8, 0) CWRITE(7, lsA[0])
    CWRITE(8, lsA[0])
    asm volatile("s_waitcnt lgkmcnt(0)" ::: "memory");
    __builtin_amdgcn_s_barrier();
    __builtin_amdgcn_sched_barrier(0);

    // ---- main loop: 16 K-slices (32 x-cols each) x 16 t-steps ----
    for (int sl = 0; sl < 16; ++sl) {
        const unsigned char* La = lsA[sl & 1];
        unsigned char* Ln = lsA[(sl + 1) & 1];
        const int q16 = sl << 4;
        const int qn = sl + 1;
        const int pf = (sl < 15);

        TSTEP(0, La, Bc, Bn)
        if (pf) { CISSUE(0, qn) CISSUE(1, qn) }
        TSTEP(1, La, Bn, Bc)
        if (pf) { CWRITE(0, Ln) CISSUE(2, qn) }
        TSTEP(2, La, Bc, Bn)
        if (pf) { CWRITE(1, Ln) CISSUE(3, qn) }
        TSTEP(3, La, Bn, Bc)
        if (pf) { CWRITE(2, Ln) CISSUE(4, qn) }
        TSTEP(4, La, Bc, Bn)
        if (pf) { CWRITE(3, Ln) CISSUE(5, qn) }
        TSTEP(5, La, Bn, Bc)
        if (pf) { CWRITE(4, Ln) CISSUE(6, qn) }
        TSTEP(6, La, Bc, Bn)
        if (pf) { CWRITE(5, Ln) CISSUE(7, qn) }
        TSTEP(7, La, Bn, Bc)
        if (pf) { CWRITE(6, Ln) CISSUE(8, qn) }
        TSTEP(8, La, Bc, Bn)
        if (pf) { CWRITE(7, Ln) }
        TSTEP(9, La, Bn, Bc)
        if (pf) { CWRITE(8, Ln) }
        TSTEP(10, La, Bc, Bn)
        TSTEP(11, La, Bn, Bc)
        TSTEP(12, La, Bc, Bn)
        TSTEP(13, La, Bn, Bc)
        TSTEP(14, La, Bc, Bn)
        TSTEP(15, La, Bn, Bc)

        asm volatile("s_waitcnt lgkmcnt(0)" ::: "memory");
        __builtin_amdgcn_s_barrier();
        __builtin_amdgcn_sched_barrier(0);
    }
#undef TSTEP
#undef CISSUE
#undef CWRITE

    // ---- epilogue: bias + exact GELU -> hbuf[b][win][d] ----
    const int dbase = ((nc * 4 + wc) << 6) + r15;
    float bias4[4];
#pragma unroll
    for (int n = 0; n < 4; ++n)
        bias4[n] = bias[dbase + (n << 4)];
    float* hb = hbuf + (size_t)b * NWIN * D_DIM;
#pragma unroll
    for (int m = 0; m < 4; ++m) {
#pragma unroll
        for (int r = 0; r < 4; ++r) {
            int win = win0 + (wr << 6) + (m << 4) + (hi << 2) + r;
            if (win < NWIN) {
                float* dst = hb + (size_t)win * D_DIM + dbase;
#pragma unroll
                for (int n = 0; n < 4; ++n) {
                    float h = acc[m][n][r] + bias4[n];
                    dst[n << 4] = 0.5f * h * (1.0f + erff(h * 0.70710678118654752f));
                }
            }
        }
    }
}

// ---------------------------------------------------------------------------
// Kernel B: row LayerNorm over D=512. One wave per row, grid-stride. (verified)
// ---------------------------------------------------------------------------
__global__ __launch_bounds__(256, 8)
void ln_kernel(const float* __restrict__ h, const float* __restrict__ gamma,
               const float* __restrict__ beta, float* __restrict__ out, int nrows)
{
    const int lane = threadIdx.x & 63;
    const int wv = blockIdx.x * 4 + (threadIdx.x >> 6);
    const int nw = gridDim.x * 4;
    float gm[8], bt[8];
#pragma unroll
    for (int j = 0; j < 8; ++j) {
        gm[j] = gamma[lane * 8 + j];
        bt[j] = beta[lane * 8 + j];
    }
    for (int row = wv; row < nrows; row += nw) {
        const float* src = h + (size_t)row * D_DIM + lane * 8;
        float4 v0 = *(const float4*)src;
        float4 v1 = *(const float4*)(src + 4);
        float s = v0.x + v0.y + v0.z + v0.w + v1.x + v1.y + v1.z + v1.w;
        float q = v0.x * v0.x + v0.y * v0.y + v0.z * v0.z + v0.w * v0.w +
                  v1.x * v1.x + v1.y * v1.y + v1.z * v1.z + v1.w * v1.w;
#pragma unroll
        for (int msk = 1; msk < 64; msk <<= 1) {
            s += __shfl_xor(s, msk, 64);
            q += __shfl_xor(q, msk, 64);
        }
        float mu  = s * (1.0f / 512.0f);
        float inv = rsqrtf(q * (1.0f / 512.0f) - mu * mu + 1e-5f);
        float o[8] = { v0.x, v0.y, v0.z, v0.w, v1.x, v1.y, v1.z, v1.w };
        float4 r0, r1;
        r0.x = (o[0] - mu) * inv * gm[0] + bt[0];
        r0.y = (o[1] - mu) * inv * gm[1] + bt[1];
        r0.z = (o[2] - mu) * inv * gm[2] + bt[2];
        r0.w = (o[3] - mu) * inv * gm[3] + bt[3];
        r1.x = (o[4] - mu) * inv * gm[4] + bt[4];
        r1.y = (o[5] - mu) * inv * gm[5] + bt[5];
        r1.z = (o[6] - mu) * inv * gm[6] + bt[6];
        r1.w = (o[7] - mu) * inv * gm[7] + bt[7];
        float* dst = out + (size_t)row * D_DIM + lane * 8;
        *(float4*)dst = r0;
        *(float4*)(dst + 4) = r1;
    }
}

// Fallback (tiny ws): naive correct kernel.
__global__ void naive_kernel(const float* __restrict__ x, const float* __restrict__ W,
                             const float* __restrict__ bias, const float* __restrict__ gamma,
                             const float* __restrict__ beta, float* __restrict__ out) {
    __shared__ float hrow[D_DIM];
    __shared__ float red[2];
    const int b = blockIdx.x / NWIN, win = blockIdx.x % NWIN;
    const int d = threadIdx.x;
    float a = 0.f;
    for (int t = 0; t < 16; ++t) {
        const float* xr = x + ((size_t)b * S_LEN + 8 * win + t) * D_DIM;
        const float* wr = W + (size_t)t * D_DIM * D_DIM;
        for (int k = 0; k < D_DIM; ++k) a += xr[k] * wr[(size_t)k * D_DIM + d];
    }
    a += bias[d];
    a = 0.5f * a * (1.0f + erff(a * 0.70710678118654752f));
    hrow[d] = a;
    __syncthreads();
    if (d == 0) {
        float s = 0.f, q = 0.f;
        for (int k = 0; k < D_DIM; ++k) { s += hrow[k]; q += hrow[k] * hrow[k]; }
        float mu = s / D_DIM;
        red[0] = mu; red[1] = rsqrtf(q / D_DIM - mu * mu + 1e-5f);
    }
    __syncthreads();
    out[((size_t)b * NWIN + win) * D_DIM + d] = (a - red[0]) * red[1] * gamma[d] + beta[d];
}

extern "C" void kernel_launch(void* const* d_in, const int* in_sizes, int n_in,
                              void* d_out, int out_size, void* d_ws, size_t ws_size,
                              hipStream_t stream) {
    const float* x     = (const float*)d_in[0];
    const float* W     = (const float*)d_in[1];
    const float* bias  = (const float*)d_in[2];
    const float* gamma = (const float*)d_in[3];
    const float* beta  = (const float*)d_in[4];
    float* out = (float*)d_out;

    const size_t pk_bytes = (size_t)KDIM * D_DIM * sizeof(unsigned short);     // 8 MB
    const size_t h_bytes  = (size_t)32 * NWIN * D_DIM * sizeof(float);         // 33.5 MB

    if (ws_size >= pk_bytes + h_bytes) {          // proven available (R4/R8)
        short8* pk = (short8*)d_ws;
        float* hbuf = (float*)((char*)d_ws + pk_bytes);
        wpack2_kernel<<<1024, 256, 0, stream>>>(W, pk);
        gemm3_kernel<<<256, 512, 0, stream>>>(x, pk, bias, hbuf);
        ln_kernel<<<1024, 256, 0, stream>>>(hbuf, gamma, beta, out, 32 * NWIN);
    } else {
        naive_kernel<<<32 * NWIN, D_DIM, 0, stream>>>(x, W, bias, gamma, beta, out);
    }
}